// Round 11
// baseline (524.128 us; speedup 1.0000x reference)
//
#include <hip/hip_runtime.h>
#include <math.h>

// Problem constants (fixed by setup_inputs)
constexpr int Bc  = 32;     // batch
constexpr int Dc  = 256;    // word feature dim
constexpr int Tc  = 32;     // seq len
constexpr int DHc = 128;    // image feature dim
constexpr int Nc  = 16384;  // H*W = 128*128

typedef _Float16 v8hf __attribute__((ext_vector_type(8)));
typedef _Float16 v2hf __attribute__((ext_vector_type(2)));
typedef float    v4f  __attribute__((ext_vector_type(4)));
typedef float    v16f __attribute__((ext_vector_type(16)));

// ---------------------------------------------------------------------------
// Stage 1: V = W·wf_b + bias, emitted directly as split-f16 buffers:
//   vth [b][t][k] (f16 hi)   vtl [b][t][k] (f16 lo)   vph [b][k][t] (f16 hi)
// grid: 32 b × 8 k-blocks of 16 = 256 blocks, 256 threads.  (unchanged)
// ---------------------------------------------------------------------------
__global__ __launch_bounds__(256) void values_kernel(
    const float* __restrict__ wf, const float* __restrict__ Wm,
    const float* __restrict__ bias,
    _Float16* __restrict__ vth, _Float16* __restrict__ vtl,
    _Float16* __restrict__ vph)
{
    __shared__ float wfs[Dc * Tc];        // 32 KB  [d][t]  (reused by epilogue)
    __shared__ float Ws[16 * 260];        // 16.6 KB, padded rows

    const int tid = threadIdx.x;
    const int b   = blockIdx.x >> 3;
    const int k0  = (blockIdx.x & 7) * 16;

    {   // stage wf[b]: 8192 floats, coalesced float4
        const float4* src = (const float4*)(wf + (size_t)b * Dc * Tc);
        float4* dst = (float4*)wfs;
        #pragma unroll
        for (int i = 0; i < 8; ++i) dst[tid + 256 * i] = src[tid + 256 * i];
    }
    {   // stage W rows k0..k0+15: 4096 floats
        #pragma unroll
        for (int i = 0; i < 4; ++i) {
            int f = tid + 256 * i;            // float4 index
            int row = f >> 6, d4 = f & 63;
            *(float4*)&Ws[row * 260 + 4 * d4] =
                *(const float4*)&Wm[(size_t)(k0 + row) * Dc + 4 * d4];
        }
    }
    __syncthreads();

    const int kl  = tid >> 4;          // 0..15
    const int tt0 = (tid & 15) * 2;    // even t
    const int k   = k0 + kl;

    float acc0 = bias[k], acc1 = acc0;
    #pragma unroll
    for (int d4 = 0; d4 < 64; ++d4) {
        const float4 w4 = *(const float4*)&Ws[kl * 260 + 4 * d4];
        #pragma unroll
        for (int j = 0; j < 4; ++j) {
            const float2 f2 = *(const float2*)&wfs[(4 * d4 + j) * Tc + tt0];
            const float wv = (j == 0) ? w4.x : (j == 1) ? w4.y : (j == 2) ? w4.z : w4.w;
            acc0 = fmaf(wv, f2.x, acc0);
            acc1 = fmaf(wv, f2.y, acc1);
        }
    }

    _Float16 vh0 = (_Float16)acc0, vh1 = (_Float16)acc1;
    _Float16 vl0 = (_Float16)(acc0 - (float)vh0);
    _Float16 vl1 = (_Float16)(acc1 - (float)vh1);

    // ---- epilogue: LDS transpose staging, then coalesced uint4 writes ----
    __syncthreads();                         // done reading wfs
    _Float16* sh_h = (_Float16*)wfs;         // [16][32]  k-major (for vph)
    _Float16* th_h = sh_h + 16 * 32;         // [32][24]  t-major, padded (vth)
    _Float16* th_l = th_h + 32 * 24;         // [32][24]  t-major, padded (vtl)

    sh_h[kl * 32 + tt0]     = vh0;
    sh_h[kl * 32 + tt0 + 1] = vh1;
    th_h[tt0 * 24 + kl]       = vh0;
    th_h[(tt0 + 1) * 24 + kl] = vh1;
    th_l[tt0 * 24 + kl]       = vl0;
    th_l[(tt0 + 1) * 24 + kl] = vl1;
    __syncthreads();

    if (tid < 64) {          // vph [b][k0+row][t]: 16 rows x 64B, full segments
        int row = tid >> 2, ch = (tid & 3) * 8;
        *(uint4*)&vph[((size_t)b * DHc + k0 + row) * Tc + ch] =
            *(uint4*)&sh_h[row * 32 + ch];
    } else if (tid < 128) {  // vth [b][t][k0..k0+15]: 32 rows x 32B chunks
        int i = tid - 64; int t = i >> 1, hf = (i & 1) * 8;
        *(uint4*)&vth[((size_t)b * Tc + t) * DHc + k0 + hf] =
            *(uint4*)&th_h[t * 24 + hf];
    } else if (tid < 192) {  // vtl likewise
        int i = tid - 128; int t = i >> 1, hf = (i & 1) * 8;
        *(uint4*)&vtl[((size_t)b * Tc + t) * DHc + k0 + hf] =
            *(uint4*)&th_l[t * 24 + hf];
    }
}

// ---------------------------------------------------------------------------
// Stage 2 (MFMA 32x32x16): per 256-px strip (grid 2048), 32 px per wave/iter.
//  QK: Sᵀ[t=0..31][px=0..31] via A=Vᵀ(t,k), B=Q(k,px); 8 k-steps × 3 terms.
//  Fragment maps (by analogy with working 16x16 code + guide's 32x32 C/D):
//    A: row=lane&31, k=8*(lane>>5)+j     B: col=lane&31, k=8*(lane>>5)+j
//    C/D: col=lane&31, row=(reg&3)+8*(reg>>2)+4*(lane>>5)
//  Softmax: 16 t-values in-lane + one shfl_xor(32).
//  PV: O[px][k] via A=P(px,t), B=V(t,k); P relayout = 8 shfl_xor(32).
// ---------------------------------------------------------------------------
__global__ __launch_bounds__(256) void attn_kernel(
    const float* __restrict__ img,
    const _Float16* __restrict__ vth, const _Float16* __restrict__ vtl,
    const _Float16* __restrict__ vph,
    const int* __restrict__ mask, float* __restrict__ attn,
    float* __restrict__ coeff)
{
    constexpr int VT_LD = 136;  // k-stride (halves); 272B rows, 16B aligned
    constexpr int VP_LD = 40;   // t-stride (halves); 80B rows, 16B aligned
    __shared__ __align__(16) _Float16 VTh[Tc * VT_LD];
    __shared__ __align__(16) _Float16 VTl[Tc * VT_LD];
    __shared__ __align__(16) _Float16 VPh[DHc * VP_LD];
    __shared__ float mneg[Tc];              // total ~27.8 KB

    const int tid   = threadIdx.x;
    const int b     = blockIdx.x >> 6;      // 64 strips per batch
    const int strip = blockIdx.x & 63;

    {   // staging: pure copies (512 chunks of 16B per buffer)
        const uint4* sth = (const uint4*)(vth + (size_t)b * Tc * DHc);
        const uint4* stl = (const uint4*)(vtl + (size_t)b * Tc * DHc);
        const uint4* sph = (const uint4*)(vph + (size_t)b * DHc * Tc);
        #pragma unroll
        for (int i = 0; i < 2; ++i) {
            int cid = tid + 256 * i;
            int t = cid >> 4, cc = cid & 15;        // 16 chunks per 128-half row
            *(uint4*)&VTh[t * VT_LD + 8 * cc] = sth[cid];
            *(uint4*)&VTl[t * VT_LD + 8 * cc] = stl[cid];
            int kk = cid >> 2, c4 = cid & 3;        // 4 chunks per 32-half row
            *(uint4*)&VPh[kk * VP_LD + 8 * c4] = sph[cid];
        }
        if (tid < Tc) mneg[tid] = mask[b * Tc + tid] ? -INFINITY : 0.0f;
    }
    __syncthreads();

    const int lane = tid & 63;
    const int wave = tid >> 6;
    const int l31  = lane & 31;   // pixel column (QK/PV N-col or M-row)
    const int h    = lane >> 5;   // k-group / t-half selector

    // additive mask per C/D reg: t = (r&3) + 8*(r>>2) + 4*h
    float madd[16];
    #pragma unroll
    for (int r = 0; r < 16; ++r)
        madd[r] = mneg[(r & 3) + 8 * (r >> 2) + 4 * h];

    const float* qbase = img  + ((size_t)b * DHc + 8 * h) * Nc + l31;
    float*       cbase = coeff + (size_t)b * Nc * Tc;

    for (int it = 0; it < 2; ++it) {
        const int n0 = strip * 256 + it * 128 + wave * 32;

        // ---- load Q (B-frag: col=l31 → 128B-coalesced; k=ks*16+8h+j) ----
        const float* qp = qbase + n0;
        float q[8][8];
        #pragma unroll
        for (int ks = 0; ks < 8; ++ks)
            #pragma unroll
            for (int j = 0; j < 8; ++j)
                q[ks][j] = qp[(size_t)(ks * 16 + j) * Nc];

        v8hf Qh[8], Ql[8];
        #pragma unroll
        for (int ks = 0; ks < 8; ++ks)
            #pragma unroll
            for (int j = 0; j < 8; ++j) {
                _Float16 hh = (_Float16)q[ks][j];
                Qh[ks][j] = hh;
                Ql[ks][j] = (_Float16)(q[ks][j] - (float)hh);
            }

        // ---- Sᵀ = Vᵀ·Q : 8 k-steps × 3 split terms (24 MFMA) ----
        v16f Sh = {0.f}, Sl = {0.f};
        #pragma unroll
        for (int r = 0; r < 16; ++r) { Sh[r] = 0.f; Sl[r] = 0.f; }
        #pragma unroll
        for (int ks = 0; ks < 8; ++ks) {
            v8hf va = *(const v8hf*)&VTh[l31 * VT_LD + ks * 16 + 8 * h];
            v8hf vl = *(const v8hf*)&VTl[l31 * VT_LD + ks * 16 + 8 * h];
            Sh = __builtin_amdgcn_mfma_f32_32x32x16_f16(va, Qh[ks], Sh, 0, 0, 0);
            Sl = __builtin_amdgcn_mfma_f32_32x32x16_f16(va, Ql[ks], Sl, 0, 0, 0);
            Sl = __builtin_amdgcn_mfma_f32_32x32x16_f16(vl, Qh[ks], Sl, 0, 0, 0);
        }

        // ---- masked softmax over t: 16 in-lane + one cross-half shfl ----
        float p[16];
        float m = -INFINITY;
        #pragma unroll
        for (int r = 0; r < 16; ++r) {
            p[r] = Sh[r] + Sl[r] + madd[r];
            m = fmaxf(m, p[r]);
        }
        m = fmaxf(m, __shfl_xor(m, 32));
        float sum = 0.0f;
        #pragma unroll
        for (int r = 0; r < 16; ++r) {
            p[r] = __expf(p[r] - m);
            sum += p[r];
        }
        sum += __shfl_xor(sum, 32);
        const float inv = 1.0f / sum;
        #pragma unroll
        for (int r = 0; r < 16; ++r) p[r] *= inv;

        // ---- coefficients [B,N,T]: 4 float4 per lane (t = 4h+8rg+rr) ----
        {
            float* cp = cbase + (size_t)(n0 + l31) * Tc + 4 * h;
            #pragma unroll
            for (int rg = 0; rg < 4; ++rg)
                *(float4*)(cp + 8 * rg) =
                    make_float4(p[4*rg], p[4*rg+1], p[4*rg+2], p[4*rg+3]);
        }

        // ---- P → f16 pairs, exchange halves (lane ^ 32), build PV A-frags ----
        int u[8];
        #pragma unroll
        for (int i = 0; i < 8; ++i) {
            v2hf d; d[0] = (_Float16)p[2*i]; d[1] = (_Float16)p[2*i+1];
            u[i] = __builtin_bit_cast(int, d);
        }
        int pu[8];
        #pragma unroll
        for (int i = 0; i < 8; ++i) pu[i] = __shfl_xor(u[i], 32);

        // kh=0: h0 {d0,d1,pd0,pd1} | h1 {pd2,pd3,d2,d3}
        // kh=1: h0 {d4,d5,pd4,pd5} | h1 {pd6,pd7,d6,d7}
        int4 a0 = h == 0 ? make_int4(u[0], u[1], pu[0], pu[1])
                         : make_int4(pu[2], pu[3], u[2], u[3]);
        int4 a1 = h == 0 ? make_int4(u[4], u[5], pu[4], pu[5])
                         : make_int4(pu[6], pu[7], u[6], u[7]);
        v8hf PA0 = __builtin_bit_cast(v8hf, a0);
        v8hf PA1 = __builtin_bit_cast(v8hf, a1);

        // ---- O = P·Vᵀ : 4 k-tiles × 2 t-halves (8 MFMA); row=pixel → f4 stores
        #pragma unroll
        for (int mt = 0; mt < 4; ++mt) {
            v8hf vb0 = *(const v8hf*)&VPh[(mt * 32 + l31) * VP_LD + 8 * h];
            v8hf vb1 = *(const v8hf*)&VPh[(mt * 32 + l31) * VP_LD + 16 + 8 * h];
            v16f O;
            #pragma unroll
            for (int r = 0; r < 16; ++r) O[r] = 0.f;
            O = __builtin_amdgcn_mfma_f32_32x32x16_f16(PA0, vb0, O, 0, 0, 0);
            O = __builtin_amdgcn_mfma_f32_32x32x16_f16(PA1, vb1, O, 0, 0, 0);
            float* ap = attn + ((size_t)b * DHc + mt * 32 + l31) * Nc + n0 + 4 * h;
            #pragma unroll
            for (int rg = 0; rg < 4; ++rg)
                *(float4*)(ap + 8 * rg) =
                    make_float4(O[4*rg], O[4*rg+1], O[4*rg+2], O[4*rg+3]);
        }
    }
}

extern "C" void kernel_launch(void* const* d_in, const int* in_sizes, int n_in,
                              void* d_out, int out_size, void* d_ws, size_t ws_size,
                              hipStream_t stream)
{
    const float* wf   = (const float*)d_in[0];  // [B,D,T]
    const float* img  = (const float*)d_in[1];  // [B,Dh,H,W]
    const int*   msk  = (const int*)d_in[2];    // [B,T]
    const float* Wm   = (const float*)d_in[3];  // [Dh,D]
    const float* bias = (const float*)d_in[4];  // [Dh]

    float* attn  = (float*)d_out;                        // [B,Dh,N]
    float* coeff = attn + (size_t)Bc * DHc * Nc;         // [B,N,T]

    // workspace: three split-f16 buffers of B*Dh*T halves each (256 KB each)
    _Float16* vth = (_Float16*)d_ws;
    _Float16* vtl = vth + (size_t)Bc * DHc * Tc;
    _Float16* vph = vtl + (size_t)Bc * DHc * Tc;

    values_kernel<<<256, 256, 0, stream>>>(wf, Wm, bias, vth, vtl, vph);
    attn_kernel<<<Bc * 64, 256, 0, stream>>>(img, vth, vtl, vph, msk, attn, coeff);
}

// Round 12
// 522.206 us; speedup vs baseline: 1.0037x; 1.0037x over previous
//
#include <hip/hip_runtime.h>
#include <math.h>

// Problem constants (fixed by setup_inputs)
constexpr int Bc  = 32;     // batch
constexpr int Dc  = 256;    // word feature dim
constexpr int Tc  = 32;     // seq len
constexpr int DHc = 128;    // image feature dim
constexpr int Nc  = 16384;  // H*W = 128*128

typedef _Float16 v8hf __attribute__((ext_vector_type(8)));
typedef _Float16 v2hf __attribute__((ext_vector_type(2)));
typedef float    v4f  __attribute__((ext_vector_type(4)));
typedef float    v16f __attribute__((ext_vector_type(16)));

// ---------------------------------------------------------------------------
// Stage 1: V = W·wf_b + bias, emitted directly as split-f16 buffers:
//   vth [b][t][k] (f16 hi)   vtl [b][t][k] (f16 lo)   vph [b][k][t] (f16 hi)
// grid: 32 b × 8 k-blocks of 16 = 256 blocks, 256 threads.  (unchanged)
// ---------------------------------------------------------------------------
__global__ __launch_bounds__(256) void values_kernel(
    const float* __restrict__ wf, const float* __restrict__ Wm,
    const float* __restrict__ bias,
    _Float16* __restrict__ vth, _Float16* __restrict__ vtl,
    _Float16* __restrict__ vph)
{
    __shared__ float wfs[Dc * Tc];        // 32 KB  [d][t]  (reused by epilogue)
    __shared__ float Ws[16 * 260];        // 16.6 KB, padded rows

    const int tid = threadIdx.x;
    const int b   = blockIdx.x >> 3;
    const int k0  = (blockIdx.x & 7) * 16;

    {   // stage wf[b]: 8192 floats, coalesced float4
        const float4* src = (const float4*)(wf + (size_t)b * Dc * Tc);
        float4* dst = (float4*)wfs;
        #pragma unroll
        for (int i = 0; i < 8; ++i) dst[tid + 256 * i] = src[tid + 256 * i];
    }
    {   // stage W rows k0..k0+15: 4096 floats
        #pragma unroll
        for (int i = 0; i < 4; ++i) {
            int f = tid + 256 * i;            // float4 index
            int row = f >> 6, d4 = f & 63;
            *(float4*)&Ws[row * 260 + 4 * d4] =
                *(const float4*)&Wm[(size_t)(k0 + row) * Dc + 4 * d4];
        }
    }
    __syncthreads();

    const int kl  = tid >> 4;          // 0..15
    const int tt0 = (tid & 15) * 2;    // even t
    const int k   = k0 + kl;

    float acc0 = bias[k], acc1 = acc0;
    #pragma unroll
    for (int d4 = 0; d4 < 64; ++d4) {
        const float4 w4 = *(const float4*)&Ws[kl * 260 + 4 * d4];
        #pragma unroll
        for (int j = 0; j < 4; ++j) {
            const float2 f2 = *(const float2*)&wfs[(4 * d4 + j) * Tc + tt0];
            const float wv = (j == 0) ? w4.x : (j == 1) ? w4.y : (j == 2) ? w4.z : w4.w;
            acc0 = fmaf(wv, f2.x, acc0);
            acc1 = fmaf(wv, f2.y, acc1);
        }
    }

    _Float16 vh0 = (_Float16)acc0, vh1 = (_Float16)acc1;
    _Float16 vl0 = (_Float16)(acc0 - (float)vh0);
    _Float16 vl1 = (_Float16)(acc1 - (float)vh1);

    // ---- epilogue: LDS transpose staging, then coalesced uint4 writes ----
    __syncthreads();                         // done reading wfs
    _Float16* sh_h = (_Float16*)wfs;         // [16][32]  k-major (for vph)
    _Float16* th_h = sh_h + 16 * 32;         // [32][24]  t-major, padded (vth)
    _Float16* th_l = th_h + 32 * 24;         // [32][24]  t-major, padded (vtl)

    sh_h[kl * 32 + tt0]     = vh0;
    sh_h[kl * 32 + tt0 + 1] = vh1;
    th_h[tt0 * 24 + kl]       = vh0;
    th_h[(tt0 + 1) * 24 + kl] = vh1;
    th_l[tt0 * 24 + kl]       = vl0;
    th_l[(tt0 + 1) * 24 + kl] = vl1;
    __syncthreads();

    if (tid < 64) {          // vph [b][k0+row][t]: 16 rows x 64B, full segments
        int row = tid >> 2, ch = (tid & 3) * 8;
        *(uint4*)&vph[((size_t)b * DHc + k0 + row) * Tc + ch] =
            *(uint4*)&sh_h[row * 32 + ch];
    } else if (tid < 128) {  // vth [b][t][k0..k0+15]: 32 rows x 32B chunks
        int i = tid - 64; int t = i >> 1, hf = (i & 1) * 8;
        *(uint4*)&vth[((size_t)b * Tc + t) * DHc + k0 + hf] =
            *(uint4*)&th_h[t * 24 + hf];
    } else if (tid < 192) {  // vtl likewise
        int i = tid - 128; int t = i >> 1, hf = (i & 1) * 8;
        *(uint4*)&vtl[((size_t)b * Tc + t) * DHc + k0 + hf] =
            *(uint4*)&th_l[t * 24 + hf];
    }
}

// ---------------------------------------------------------------------------
// Stage 2 (MFMA 32x32x16): per 256-px strip (grid 2048), 32 px per wave/iter.
//  Same fragment maps as r11 (verified by passing refcheck):
//    A: row=lane&31, k=8*(lane>>5)+j     B: col=lane&31, k=8*(lane>>5)+j
//    C/D: col=lane&31, row=(reg&3)+8*(reg>>2)+4*(lane>>5)
//  CHANGE vs r11: Q converted to f16 hi/lo INLINE (no q[8][8] f32 buffer)
//  → ~64 fewer live VGPRs → more waves/SIMD (the r2/r4 pattern).
// ---------------------------------------------------------------------------
__global__ __launch_bounds__(256) void attn_kernel(
    const float* __restrict__ img,
    const _Float16* __restrict__ vth, const _Float16* __restrict__ vtl,
    const _Float16* __restrict__ vph,
    const int* __restrict__ mask, float* __restrict__ attn,
    float* __restrict__ coeff)
{
    constexpr int VT_LD = 136;  // k-stride (halves); 272B rows, 16B aligned
    constexpr int VP_LD = 40;   // t-stride (halves); 80B rows, 16B aligned
    __shared__ __align__(16) _Float16 VTh[Tc * VT_LD];
    __shared__ __align__(16) _Float16 VTl[Tc * VT_LD];
    __shared__ __align__(16) _Float16 VPh[DHc * VP_LD];
    __shared__ float mneg[Tc];              // total ~27.8 KB

    const int tid   = threadIdx.x;
    const int b     = blockIdx.x >> 6;      // 64 strips per batch
    const int strip = blockIdx.x & 63;

    {   // staging: pure copies (512 chunks of 16B per buffer)
        const uint4* sth = (const uint4*)(vth + (size_t)b * Tc * DHc);
        const uint4* stl = (const uint4*)(vtl + (size_t)b * Tc * DHc);
        const uint4* sph = (const uint4*)(vph + (size_t)b * DHc * Tc);
        #pragma unroll
        for (int i = 0; i < 2; ++i) {
            int cid = tid + 256 * i;
            int t = cid >> 4, cc = cid & 15;        // 16 chunks per 128-half row
            *(uint4*)&VTh[t * VT_LD + 8 * cc] = sth[cid];
            *(uint4*)&VTl[t * VT_LD + 8 * cc] = stl[cid];
            int kk = cid >> 2, c4 = cid & 3;        // 4 chunks per 32-half row
            *(uint4*)&VPh[kk * VP_LD + 8 * c4] = sph[cid];
        }
        if (tid < Tc) mneg[tid] = mask[b * Tc + tid] ? -INFINITY : 0.0f;
    }
    __syncthreads();

    const int lane = tid & 63;
    const int wave = tid >> 6;
    const int l31  = lane & 31;   // pixel column (QK/PV N-col or M-row)
    const int h    = lane >> 5;   // k-group / t-half selector

    // additive mask per C/D reg: t = (r&3) + 8*(r>>2) + 4*h
    float madd[16];
    #pragma unroll
    for (int r = 0; r < 16; ++r)
        madd[r] = mneg[(r & 3) + 8 * (r >> 2) + 4 * h];

    const float* qbase = img  + ((size_t)b * DHc + 8 * h) * Nc + l31;
    float*       cbase = coeff + (size_t)b * Nc * Tc;

    for (int it = 0; it < 2; ++it) {
        const int n0 = strip * 256 + it * 128 + wave * 32;

        // ---- load Q inline → f16 hi/lo fragments (no f32 staging buffer) ----
        const float* qp = qbase + n0;
        v8hf Qh[8], Ql[8];
        #pragma unroll
        for (int ks = 0; ks < 8; ++ks)
            #pragma unroll
            for (int j = 0; j < 8; ++j) {
                float qv = qp[(size_t)(ks * 16 + j) * Nc];
                _Float16 hh = (_Float16)qv;
                Qh[ks][j] = hh;
                Ql[ks][j] = (_Float16)(qv - (float)hh);
            }

        // ---- Sᵀ = Vᵀ·Q : 8 k-steps × 3 split terms (24 MFMA) ----
        v16f Sh, Sl;
        #pragma unroll
        for (int r = 0; r < 16; ++r) { Sh[r] = 0.f; Sl[r] = 0.f; }
        #pragma unroll
        for (int ks = 0; ks < 8; ++ks) {
            v8hf va = *(const v8hf*)&VTh[l31 * VT_LD + ks * 16 + 8 * h];
            v8hf vl = *(const v8hf*)&VTl[l31 * VT_LD + ks * 16 + 8 * h];
            Sh = __builtin_amdgcn_mfma_f32_32x32x16_f16(va, Qh[ks], Sh, 0, 0, 0);
            Sl = __builtin_amdgcn_mfma_f32_32x32x16_f16(va, Ql[ks], Sl, 0, 0, 0);
            Sl = __builtin_amdgcn_mfma_f32_32x32x16_f16(vl, Qh[ks], Sl, 0, 0, 0);
        }

        // ---- masked softmax over t: 16 in-lane + one cross-half shfl ----
        float p[16];
        float m = -INFINITY;
        #pragma unroll
        for (int r = 0; r < 16; ++r) {
            p[r] = Sh[r] + Sl[r] + madd[r];
            m = fmaxf(m, p[r]);
        }
        m = fmaxf(m, __shfl_xor(m, 32));
        float sum = 0.0f;
        #pragma unroll
        for (int r = 0; r < 16; ++r) {
            p[r] = __expf(p[r] - m);
            sum += p[r];
        }
        sum += __shfl_xor(sum, 32);
        const float inv = 1.0f / sum;
        #pragma unroll
        for (int r = 0; r < 16; ++r) p[r] *= inv;

        // ---- coefficients [B,N,T]: 4 float4 per lane (t = 4h+8rg+rr) ----
        {
            float* cp = cbase + (size_t)(n0 + l31) * Tc + 4 * h;
            #pragma unroll
            for (int rg = 0; rg < 4; ++rg)
                *(float4*)(cp + 8 * rg) =
                    make_float4(p[4*rg], p[4*rg+1], p[4*rg+2], p[4*rg+3]);
        }

        // ---- P → f16 pairs, exchange halves (lane ^ 32), build PV A-frags ----
        int u[8];
        #pragma unroll
        for (int i = 0; i < 8; ++i) {
            v2hf d; d[0] = (_Float16)p[2*i]; d[1] = (_Float16)p[2*i+1];
            u[i] = __builtin_bit_cast(int, d);
        }
        int pu[8];
        #pragma unroll
        for (int i = 0; i < 8; ++i) pu[i] = __shfl_xor(u[i], 32);

        // kh=0: h0 {d0,d1,pd0,pd1} | h1 {pd2,pd3,d2,d3}
        // kh=1: h0 {d4,d5,pd4,pd5} | h1 {pd6,pd7,d6,d7}
        int4 a0 = h == 0 ? make_int4(u[0], u[1], pu[0], pu[1])
                         : make_int4(pu[2], pu[3], u[2], u[3]);
        int4 a1 = h == 0 ? make_int4(u[4], u[5], pu[4], pu[5])
                         : make_int4(pu[6], pu[7], u[6], u[7]);
        v8hf PA0 = __builtin_bit_cast(v8hf, a0);
        v8hf PA1 = __builtin_bit_cast(v8hf, a1);

        // ---- O = P·Vᵀ : 4 k-tiles × 2 t-halves (8 MFMA); row=pixel → f4 stores
        #pragma unroll
        for (int mt = 0; mt < 4; ++mt) {
            v8hf vb0 = *(const v8hf*)&VPh[(mt * 32 + l31) * VP_LD + 8 * h];
            v8hf vb1 = *(const v8hf*)&VPh[(mt * 32 + l31) * VP_LD + 16 + 8 * h];
            v16f O;
            #pragma unroll
            for (int r = 0; r < 16; ++r) O[r] = 0.f;
            O = __builtin_amdgcn_mfma_f32_32x32x16_f16(PA0, vb0, O, 0, 0, 0);
            O = __builtin_amdgcn_mfma_f32_32x32x16_f16(PA1, vb1, O, 0, 0, 0);
            float* ap = attn + ((size_t)b * DHc + mt * 32 + l31) * Nc + n0 + 4 * h;
            #pragma unroll
            for (int rg = 0; rg < 4; ++rg)
                *(float4*)(ap + 8 * rg) =
                    make_float4(O[4*rg], O[4*rg+1], O[4*rg+2], O[4*rg+3]);
        }
    }
}

extern "C" void kernel_launch(void* const* d_in, const int* in_sizes, int n_in,
                              void* d_out, int out_size, void* d_ws, size_t ws_size,
                              hipStream_t stream)
{
    const float* wf   = (const float*)d_in[0];  // [B,D,T]
    const float* img  = (const float*)d_in[1];  // [B,Dh,H,W]
    const int*   msk  = (const int*)d_in[2];    // [B,T]
    const float* Wm   = (const float*)d_in[3];  // [Dh,D]
    const float* bias = (const float*)d_in[4];  // [Dh]

    float* attn  = (float*)d_out;                        // [B,Dh,N]
    float* coeff = attn + (size_t)Bc * DHc * Nc;         // [B,N,T]

    // workspace: three split-f16 buffers of B*Dh*T halves each (256 KB each)
    _Float16* vth = (_Float16*)d_ws;
    _Float16* vtl = vth + (size_t)Bc * DHc * Tc;
    _Float16* vph = vtl + (size_t)Bc * DHc * Tc;

    values_kernel<<<256, 256, 0, stream>>>(wf, Wm, bias, vth, vtl, vph);
    attn_kernel<<<Bc * 64, 256, 0, stream>>>(img, vth, vtl, vph, msk, attn, coeff);
}